// Round 7
// baseline (107.331 us; speedup 1.0000x reference)
//
#include <hip/hip_runtime.h>
#include <hip/hip_bf16.h>

typedef __bf16 bf16x8 __attribute__((ext_vector_type(8)));
typedef __bf16 bf16x4 __attribute__((ext_vector_type(4)));
typedef float  f32x4  __attribute__((ext_vector_type(4)));
typedef float  f32x2  __attribute__((ext_vector_type(2)));

#define MFMA16(A, B, C) __builtin_amdgcn_mfma_f32_16x16x32_bf16(A, B, C, 0, 0, 0)
// h-write -> h-read ordering + DS drain (wave-private buffer)
#define FENCE_WAIT() do { asm volatile("s_waitcnt lgkmcnt(0)" ::: "memory"); \
                          __builtin_amdgcn_sched_barrier(0); } while (0)
// compiler-only memory fence (no instruction): stops TBAA-based reordering
#define FENCE_COMPILER() asm volatile("" ::: "memory")

struct TileRegs { f32x4 s0, s1, s2, s3; f32x4 x; };

__device__ __forceinline__ void load_tile(TileRegs& T, const float* __restrict__ s,
                                          const float* __restrict__ x,
                                          int tile, int lrow, int lg, int E)
{
  int er = tile * 16 + lrow; er = er < E ? er : E - 1;
  const float* sp = s + (size_t)er * 64 + lg * 8;
  T.s0 = *(const f32x4*)(sp);
  T.s1 = *(const f32x4*)(sp + 4);
  T.s2 = *(const f32x4*)(sp + 32);
  T.s3 = *(const f32x4*)(sp + 36);
  T.x  = *(const f32x4*)(x + (size_t)er * 8 + (lg & 1) * 4);
}

// One wave owns a contiguous balanced run of 16-edge tiles, 2-deep pipelined.
__global__ __launch_bounds__(256, 4) void so2_fused_kernel(
    const float* __restrict__ x, const float* __restrict__ s,
    const float* __restrict__ W1, const float* __restrict__ b1v,
    const float* __restrict__ W2, const float* __restrict__ b2v,
    float* __restrict__ out, int E)
{
  __shared__ unsigned short lds_w1t[64 * 64];  // W1^T [j][k] bf16, XOR-swizzled
  __shared__ unsigned short lds_w2t[32 * 64];  // W2^T [d][k] bf16, XOR-swizzled
  __shared__ char lds_h[4][2048];              // per-wave h for ONE 16-edge tile

  const int tid  = threadIdx.x;
  const int wid  = tid >> 6;
  const int lane = tid & 63;
  const int lrow = lane & 15;
  const int lg   = lane >> 4;

  // ---- biases straight to registers (loop-invariant) ----
  f32x4 bias1[4], bias2[2];
  #pragma unroll
  for (int jt = 0; jt < 4; ++jt) bias1[jt] = *(const f32x4*)(b1v + jt * 16 + lg * 4);
  #pragma unroll
  for (int dt = 0; dt < 2; ++dt) bias2[dt] = *(const f32x4*)(b2v + dt * 16 + lg * 4);

  // ---- stage weights once per block (bf16, transposed, XOR-swizzled) ----
  #pragma unroll
  for (int it = 0; it < 4; ++it) {
    int i = (it * 256 + tid) * 4;            // 4 consecutive floats, same k row
    f32x4 v = *(const f32x4*)(W1 + i);
    int k = i >> 6, j = i & 63;
    #pragma unroll
    for (int q = 0; q < 4; ++q) {
      int byte = ((j + q) << 7) + (k << 1);
      byte ^= ((j + q) & 7) << 4;
      *(unsigned short*)((char*)lds_w1t + byte) =
          __builtin_bit_cast(unsigned short, (__bf16)v[q]);
    }
  }
  #pragma unroll
  for (int it = 0; it < 2; ++it) {
    int i = (it * 256 + tid) * 4;            // i = k*32 + d
    f32x4 v = *(const f32x4*)(W2 + i);
    int k = i >> 5, d = i & 31;
    #pragma unroll
    for (int q = 0; q < 4; ++q) {
      int byte = ((d + q) << 7) + (k << 1);
      byte ^= ((d + q) & 7) << 4;
      *(unsigned short*)((char*)lds_w2t + byte) =
          __builtin_bit_cast(unsigned short, (__bf16)v[q]);
    }
  }
  __syncthreads();

  // ---- hoist W2^T fragments to registers (loop-invariant, 16 VGPR) ----
  bf16x8 w2f[2][2];
  #pragma unroll
  for (int dt = 0; dt < 2; ++dt)
    #pragma unroll
    for (int c = 0; c < 2; ++c) {
      int d = dt * 16 + lrow;
      int byte = (d << 7) + ((c * 32 + lg * 8) << 1);
      byte ^= (d & 7) << 4;
      w2f[dt][c] = *(const bf16x8*)((const char*)lds_w2t + byte);
    }

  // ---- balanced contiguous tile range for THIS WAVE ----
  const int nTiles = (E + 15) >> 4;
  const int W = gridDim.x * 4;
  const int w = blockIdx.x * 4 + wid;
  const int Tb = (int)(((long long)w * nTiles) / W);
  const int Te = (int)(((long long)(w + 1) * nTiles) / W);
  const int n = Te - Tb;
  if (n <= 0) return;                        // no barriers after this point

  char* hbuf = lds_h[wid];

  // ---- the per-tile compute (R5-proven mappings, unchanged) ----
  auto compute_store = [&](const TileRegs& T, int tile) {
    bf16x8 sf0, sf1;
    #pragma unroll
    for (int i = 0; i < 4; ++i) {
      sf0[i] = (__bf16)T.s0[i]; sf0[i + 4] = (__bf16)T.s1[i];
      sf1[i] = (__bf16)T.s2[i]; sf1[i + 4] = (__bf16)T.s3[i];
    }
    const f32x4 xe = T.x;

    // GEMM1: hT = relu(W1^T @ s^T + b1) -> 2KB wave-private LDS
    #pragma unroll
    for (int jt = 0; jt < 4; ++jt) {
      const int j = jt * 16 + lrow;
      int wb0 = (j << 7) + ((lg * 8) << 1);      wb0 ^= (j & 7) << 4;
      int wb1 = (j << 7) + ((32 + lg * 8) << 1); wb1 ^= (j & 7) << 4;
      bf16x8 wf0 = *(const bf16x8*)((const char*)lds_w1t + wb0);
      bf16x8 wf1 = *(const bf16x8*)((const char*)lds_w1t + wb1);
      f32x4 acc = bias1[jt];
      acc = MFMA16(wf0, sf0, acc);
      acc = MFMA16(wf1, sf1, acc);
      bf16x4 hv;
      #pragma unroll
      for (int r = 0; r < 4; ++r) hv[r] = (__bf16)fmaxf(acc[r], 0.f);
      int byte = (lrow << 7) + ((jt * 16 + lg * 4) << 1);
      byte ^= (lrow & 7) << 4;
      *(bf16x4*)(hbuf + byte) = hv;
    }

    FENCE_WAIT();

    // GEMM2 + in-register complex epilogue
    bf16x8 hf0, hf1;
    {
      int b0 = (lrow << 7) + ((lg * 8) << 1);      b0 ^= (lrow & 7) << 4;
      int b1 = (lrow << 7) + ((32 + lg * 8) << 1); b1 ^= (lrow & 7) << 4;
      hf0 = *(const bf16x8*)(hbuf + b0);
      hf1 = *(const bf16x8*)(hbuf + b1);
    }
    FENCE_COMPILER();  // pin h-reads above next tile's h-writes

    float qr[2], qi[2];
    #pragma unroll
    for (int dt = 0; dt < 2; ++dt) {
      f32x4 a = bias2[dt];
      a = MFMA16(w2f[dt][0], hf0, a);
      a = MFMA16(w2f[dt][1], hf1, a);
      // lane holds w[e][d = dt*16+lg*4+r]; o=2dt+(lg>>1), p=2(lg&1)+(r>>1)
      float pr = xe[0] * a[0] - xe[1] * a[1] + xe[2] * a[2] - xe[3] * a[3];
      float pi = xe[0] * a[1] + xe[1] * a[0] + xe[2] * a[3] + xe[3] * a[2];
      qr[dt] = pr + __shfl_xor(pr, 16, 64);
      qi[dt] = pi + __shfl_xor(pi, 16, 64);
    }
    const int sel = lg & 1;
    const int o = (lg >> 1) + 2 * sel;
    const float vr = sel ? qr[1] : qr[0];
    const float vi = sel ? qi[1] : qi[0];
    const int e = tile * 16 + lrow;
    if (e < E) {
      f32x2 v2 = {vr, vi};
      *(f32x2*)(out + (size_t)e * 8 + o * 2) = v2;
    }
  };

  // ---- 2-deep pipeline over contiguous tiles [Tb, Te) ----
  TileRegs A, B;
  load_tile(A, s, x, Tb, lrow, lg, E);
  load_tile(B, s, x, Tb + (n > 1 ? 1 : 0), lrow, lg, E);

  int i = 0;
  for (; i + 1 < n; i += 2) {
    TileRegs tA = A;                                   // consume, then refill
    {
      int nx = i + 2 < n ? i + 2 : n - 1;
      load_tile(A, s, x, Tb + nx, lrow, lg, E);
    }
    compute_store(tA, Tb + i);

    TileRegs tB = B;
    {
      int nx = i + 3 < n ? i + 3 : n - 1;
      load_tile(B, s, x, Tb + nx, lrow, lg, E);
    }
    compute_store(tB, Tb + i + 1);
  }
  if (i < n) compute_store(A, Tb + i);
}

extern "C" void kernel_launch(void* const* d_in, const int* in_sizes, int n_in,
                              void* d_out, int out_size, void* d_ws, size_t ws_size,
                              hipStream_t stream) {
  const float* x  = (const float*)d_in[0];
  const float* s  = (const float*)d_in[1];
  const float* W1 = (const float*)d_in[2];
  const float* b1 = (const float*)d_in[3];
  const float* W2 = (const float*)d_in[4];
  const float* b2 = (const float*)d_in[5];
  float* out = (float*)d_out;
  const int E = in_sizes[0] / 8;                 // x is (E, 4, 2)
  const int nTiles = (E + 15) / 16;
  const int maxBlocks = 1024;                    // exactly 4 blocks/CU, balanced
  const int blocks = (nTiles + 3) / 4 < maxBlocks ? (nTiles + 3) / 4 : maxBlocks;
  so2_fused_kernel<<<blocks, 256, 0, stream>>>(x, s, W1, b1, W2, b2, out, E);
}

// Round 9
// 61.448 us; speedup vs baseline: 1.7467x; 1.7467x over previous
//
#include <hip/hip_runtime.h>
#include <hip/hip_bf16.h>

typedef __bf16 bf16x8 __attribute__((ext_vector_type(8)));
typedef __bf16 bf16x4 __attribute__((ext_vector_type(4)));
typedef float  f32x4  __attribute__((ext_vector_type(4)));
typedef float  f32x2  __attribute__((ext_vector_type(2)));

#define MFMA16(A, B, C) __builtin_amdgcn_mfma_f32_16x16x32_bf16(A, B, C, 0, 0, 0)
// h-write -> h-read ordering + DS drain (wave-private buffer)
#define FENCE_WAIT() do { asm volatile("s_waitcnt lgkmcnt(0)" ::: "memory"); \
                          __builtin_amdgcn_sched_barrier(0); } while (0)
// compiler-only memory fence (no instruction): stops TBAA-based reordering
#define FENCE_COMPILER() asm volatile("" ::: "memory")

// One wave = 128 contiguous edges = 8 tiles of 16 edges, 1-deep pipelined.
// Body is byte-identical to the validated R5 kernel; only the per-wave edge
// count (256->128) and grid size changed, lifting the grid-imposed occupancy
// ceiling (R7 counters: latency-bound, occupancy was capped at ~43% by grid).
__global__ __launch_bounds__(256, 4) void so2_fused_kernel(
    const float* __restrict__ x, const float* __restrict__ s,
    const float* __restrict__ W1, const float* __restrict__ b1v,
    const float* __restrict__ W2, const float* __restrict__ b2v,
    float* __restrict__ out, int E)
{
  __shared__ unsigned short lds_w1t[64 * 64];  // W1^T [j][k] bf16, XOR-swizzled
  __shared__ unsigned short lds_w2t[32 * 64];  // W2^T [d][k] bf16, XOR-swizzled
  __shared__ char lds_h[4][2048];              // per-wave h for ONE 16-edge tile

  const int tid  = threadIdx.x;
  const int wid  = tid >> 6;
  const int lane = tid & 63;
  const int lrow = lane & 15;
  const int lg   = lane >> 4;

  // ---- biases straight to registers (loop-invariant) ----
  f32x4 bias1[4], bias2[2];
  #pragma unroll
  for (int jt = 0; jt < 4; ++jt) bias1[jt] = *(const f32x4*)(b1v + jt * 16 + lg * 4);
  #pragma unroll
  for (int dt = 0; dt < 2; ++dt) bias2[dt] = *(const f32x4*)(b2v + dt * 16 + lg * 4);

  // ---- stage weights once per block (bf16, transposed, XOR-swizzled) ----
  #pragma unroll
  for (int it = 0; it < 4; ++it) {
    int i = (it * 256 + tid) * 4;            // 4 consecutive floats, same k row
    f32x4 v = *(const f32x4*)(W1 + i);
    int k = i >> 6, j = i & 63;
    #pragma unroll
    for (int q = 0; q < 4; ++q) {
      int byte = ((j + q) << 7) + (k << 1);
      byte ^= ((j + q) & 7) << 4;
      *(unsigned short*)((char*)lds_w1t + byte) =
          __builtin_bit_cast(unsigned short, (__bf16)v[q]);
    }
  }
  #pragma unroll
  for (int it = 0; it < 2; ++it) {
    int i = (it * 256 + tid) * 4;            // i = k*32 + d
    f32x4 v = *(const f32x4*)(W2 + i);
    int k = i >> 5, d = i & 31;
    #pragma unroll
    for (int q = 0; q < 4; ++q) {
      int byte = ((d + q) << 7) + (k << 1);
      byte ^= ((d + q) & 7) << 4;
      *(unsigned short*)((char*)lds_w2t + byte) =
          __builtin_bit_cast(unsigned short, (__bf16)v[q]);
    }
  }
  __syncthreads();

  // ---- hoist W2^T fragments to registers (loop-invariant, 16 VGPR) ----
  bf16x8 w2f[2][2];
  #pragma unroll
  for (int dt = 0; dt < 2; ++dt)
    #pragma unroll
    for (int c = 0; c < 2; ++c) {
      int d = dt * 16 + lrow;
      int byte = (d << 7) + ((c * 32 + lg * 8) << 1);
      byte ^= (d & 7) << 4;
      w2f[dt][c] = *(const bf16x8*)((const char*)lds_w2t + byte);
    }

  const int wbase = blockIdx.x * 512 + wid * 128;
  const int rem = E - wbase;
  const int nt = rem <= 0 ? 0 : (rem >= 128 ? 8 : ((rem + 15) >> 4));
  if (nt == 0) return;

  char* hbuf = lds_h[wid];

  // ---- prefetch tile 0 ----
  f32x4 sN[4];
  f32x4 xN;
  {
    int er = wbase + lrow; er = er < E ? er : E - 1;
    const float* sp = s + (size_t)er * 64 + lg * 8;
    sN[0] = *(const f32x4*)(sp);
    sN[1] = *(const f32x4*)(sp + 4);
    sN[2] = *(const f32x4*)(sp + 32);
    sN[3] = *(const f32x4*)(sp + 36);
    xN = *(const f32x4*)(x + (size_t)er * 8 + (lg & 1) * 4);
  }

  for (int t = 0; t < nt; ++t) {
    const int ebase = wbase + t * 16;

    // consume prefetched tile: convert s to bf16 B-fragments
    bf16x8 sf0, sf1;
    #pragma unroll
    for (int i = 0; i < 4; ++i) {
      sf0[i] = (__bf16)sN[0][i]; sf0[i + 4] = (__bf16)sN[1][i];
      sf1[i] = (__bf16)sN[2][i]; sf1[i + 4] = (__bf16)sN[3][i];
    }
    const f32x4 xe = xN;

    // issue next tile's loads NOW (in flight across all compute below)
    {
      int er = ebase + 16 + lrow; er = er < E ? er : E - 1;
      const float* sp = s + (size_t)er * 64 + lg * 8;
      sN[0] = *(const f32x4*)(sp);
      sN[1] = *(const f32x4*)(sp + 4);
      sN[2] = *(const f32x4*)(sp + 32);
      sN[3] = *(const f32x4*)(sp + 36);
      xN = *(const f32x4*)(x + (size_t)er * 8 + (lg & 1) * 4);
    }

    // ---- GEMM1: hT = relu(W1^T @ s^T + b1) -> 2KB wave-private LDS ----
    #pragma unroll
    for (int jt = 0; jt < 4; ++jt) {
      const int j = jt * 16 + lrow;
      int wb0 = (j << 7) + ((lg * 8) << 1);      wb0 ^= (j & 7) << 4;
      int wb1 = (j << 7) + ((32 + lg * 8) << 1); wb1 ^= (j & 7) << 4;
      bf16x8 wf0 = *(const bf16x8*)((const char*)lds_w1t + wb0);
      bf16x8 wf1 = *(const bf16x8*)((const char*)lds_w1t + wb1);
      f32x4 acc = bias1[jt];
      acc = MFMA16(wf0, sf0, acc);
      acc = MFMA16(wf1, sf1, acc);
      bf16x4 hv;
      #pragma unroll
      for (int r = 0; r < 4; ++r) hv[r] = (__bf16)fmaxf(acc[r], 0.f);
      // h[edge=lrow][hid = jt*16 + lg*4 .. +3], swizzled
      int byte = (lrow << 7) + ((jt * 16 + lg * 4) << 1);
      byte ^= (lrow & 7) << 4;
      *(bf16x4*)(hbuf + byte) = hv;
    }

    FENCE_WAIT();

    // ---- GEMM2: wT = W2^T @ hT + b2 (registers), then complex epilogue ----
    bf16x8 hf0, hf1;
    {
      int b0 = (lrow << 7) + ((lg * 8) << 1);      b0 ^= (lrow & 7) << 4;
      int b1 = (lrow << 7) + ((32 + lg * 8) << 1); b1 ^= (lrow & 7) << 4;
      hf0 = *(const bf16x8*)(hbuf + b0);
      hf1 = *(const bf16x8*)(hbuf + b1);
    }
    FENCE_COMPILER();  // pin h-reads above next iteration's h-writes

    float qr[2], qi[2];
    #pragma unroll
    for (int dt = 0; dt < 2; ++dt) {
      f32x4 a = bias2[dt];
      a = MFMA16(w2f[dt][0], hf0, a);
      a = MFMA16(w2f[dt][1], hf1, a);
      // lane holds w[e=lrow][d = dt*16+lg*4+r]; o=2dt+(lg>>1), p=2(lg&1)+(r>>1)
      float pr = xe[0] * a[0] - xe[1] * a[1] + xe[2] * a[2] - xe[3] * a[3];
      float pi = xe[0] * a[1] + xe[1] * a[0] + xe[2] * a[3] + xe[3] * a[2];
      qr[dt] = pr + __shfl_xor(pr, 16, 64);
      qi[dt] = pi + __shfl_xor(pi, 16, 64);
    }
    const int sel = lg & 1;
    const int o = (lg >> 1) + 2 * sel;
    const float vr = sel ? qr[1] : qr[0];
    const float vi = sel ? qi[1] : qi[0];
    const int e = ebase + lrow;
    if (e < E) {
      f32x2 v2 = {vr, vi};
      *(f32x2*)(out + (size_t)e * 8 + o * 2) = v2;
    }
  }
}

extern "C" void kernel_launch(void* const* d_in, const int* in_sizes, int n_in,
                              void* d_out, int out_size, void* d_ws, size_t ws_size,
                              hipStream_t stream) {
  const float* x  = (const float*)d_in[0];
  const float* s  = (const float*)d_in[1];
  const float* W1 = (const float*)d_in[2];
  const float* b1 = (const float*)d_in[3];
  const float* W2 = (const float*)d_in[4];
  const float* b2 = (const float*)d_in[5];
  float* out = (float*)d_out;
  const int E = in_sizes[0] / 8;                 // x is (E, 4, 2)
  const int blocks = (E + 511) / 512;            // 128 edges/wave; ~7.6 blocks/CU
  so2_fused_kernel<<<blocks, 256, 0, stream>>>(x, s, W1, b1, W2, b2, out, E);
}

// Round 10
// 60.879 us; speedup vs baseline: 1.7630x; 1.0094x over previous
//
#include <hip/hip_runtime.h>
#include <hip/hip_bf16.h>

typedef __bf16 bf16x8 __attribute__((ext_vector_type(8)));
typedef __bf16 bf16x4 __attribute__((ext_vector_type(4)));
typedef float  f32x4  __attribute__((ext_vector_type(4)));
typedef float  f32x2  __attribute__((ext_vector_type(2)));

#define MFMA32(A, B, C) __builtin_amdgcn_mfma_f32_16x16x32_bf16(A, B, C, 0, 0, 0)

// K=16 bf16 MFMA: A/B fragments are 4 bf16 with k = (lane>>4)*4 + i — the
// SAME granularity as the 16x16 D-fragment rows, so GEMM1's output quads can
// feed GEMM2 directly in registers (no LDS round-trip, no fences).
#if __has_builtin(__builtin_amdgcn_mfma_f32_16x16x16bf16_1k)
  #define HAVE_MFMA_K16 1
  #define MFMA16(A, B, C) __builtin_amdgcn_mfma_f32_16x16x16bf16_1k(A, B, C, 0, 0, 0)
#elif __has_builtin(__builtin_amdgcn_mfma_f32_16x16x16_bf16)
  #define HAVE_MFMA_K16 1
  #define MFMA16(A, B, C) __builtin_amdgcn_mfma_f32_16x16x16_bf16(A, B, C, 0, 0, 0)
#else
  #define HAVE_MFMA_K16 0
#endif

// Fallback (LDS h round-trip) fences:
#define FENCE_WAIT() do { asm volatile("s_waitcnt lgkmcnt(0)" ::: "memory"); \
                          __builtin_amdgcn_sched_barrier(0); } while (0)
#define FENCE_COMPILER() asm volatile("" ::: "memory")

// One wave = 128 contiguous edges = 8 tiles of 16 edges, 1-deep pipelined.
// GEMM1: hT = relu(W1^T @ s^T + b1) via 16x16x32 MFMA -> bf16 quads in regs.
// GEMM2: wT = W2^T @ hT + b2 via 16x16x16 MFMA, h consumed from registers.
__global__ __launch_bounds__(256, 4) void so2_fused_kernel(
    const float* __restrict__ x, const float* __restrict__ s,
    const float* __restrict__ W1, const float* __restrict__ b1v,
    const float* __restrict__ W2, const float* __restrict__ b2v,
    float* __restrict__ out, int E)
{
  __shared__ unsigned short lds_w1t[64 * 64];  // W1^T [j][k] bf16, XOR-swizzled
  __shared__ unsigned short lds_w2t[32 * 64];  // W2^T [d][k] bf16, XOR-swizzled
#if !HAVE_MFMA_K16
  __shared__ char lds_h[4][2048];              // fallback: per-wave h buffer
#endif

  const int tid  = threadIdx.x;
  const int wid  = tid >> 6;
  const int lane = tid & 63;
  const int lrow = lane & 15;
  const int lg   = lane >> 4;

  const int wbase = blockIdx.x * 512 + wid * 128;

  // ---- tile-0 prefetch FIRST: its HBM latency hides under staging+sync ----
  f32x4 sN[4];
  f32x4 xN;
  {
    int er = wbase + lrow; er = (unsigned)er < (unsigned)E ? er : E - 1;
    if (er < 0) er = 0;
    const float* sp = s + (size_t)er * 64 + lg * 8;
    sN[0] = *(const f32x4*)(sp);
    sN[1] = *(const f32x4*)(sp + 4);
    sN[2] = *(const f32x4*)(sp + 32);
    sN[3] = *(const f32x4*)(sp + 36);
    xN = *(const f32x4*)(x + (size_t)er * 8 + (lg & 1) * 4);
  }

  // ---- biases straight to registers (loop-invariant) ----
  f32x4 bias1[4], bias2[2];
  #pragma unroll
  for (int jt = 0; jt < 4; ++jt) bias1[jt] = *(const f32x4*)(b1v + jt * 16 + lg * 4);
  #pragma unroll
  for (int dt = 0; dt < 2; ++dt) bias2[dt] = *(const f32x4*)(b2v + dt * 16 + lg * 4);

  // ---- stage weights once per block (bf16, transposed, XOR-swizzled) ----
  #pragma unroll
  for (int it = 0; it < 4; ++it) {
    int i = (it * 256 + tid) * 4;            // 4 consecutive floats, same k row
    f32x4 v = *(const f32x4*)(W1 + i);
    int k = i >> 6, j = i & 63;
    #pragma unroll
    for (int q = 0; q < 4; ++q) {
      int byte = ((j + q) << 7) + (k << 1);
      byte ^= ((j + q) & 7) << 4;
      *(unsigned short*)((char*)lds_w1t + byte) =
          __builtin_bit_cast(unsigned short, (__bf16)v[q]);
    }
  }
  #pragma unroll
  for (int it = 0; it < 2; ++it) {
    int i = (it * 256 + tid) * 4;            // i = k*32 + d
    f32x4 v = *(const f32x4*)(W2 + i);
    int k = i >> 5, d = i & 31;
    #pragma unroll
    for (int q = 0; q < 4; ++q) {
      int byte = ((d + q) << 7) + (k << 1);
      byte ^= ((d + q) & 7) << 4;
      *(unsigned short*)((char*)lds_w2t + byte) =
          __builtin_bit_cast(unsigned short, (__bf16)v[q]);
    }
  }
  __syncthreads();

  // ---- hoist W2^T fragments to registers (loop-invariant) ----
#if HAVE_MFMA_K16
  // A-frag for 16x16x16: row = d = dt*16+lrow, k = kt*16 + lg*4 + i (4 bf16)
  bf16x4 w2q[2][4];
  #pragma unroll
  for (int dt = 0; dt < 2; ++dt)
    #pragma unroll
    for (int kt = 0; kt < 4; ++kt) {
      int d = dt * 16 + lrow;
      int byte = (d << 7) + ((kt * 16 + lg * 4) << 1);
      byte ^= (d & 7) << 4;
      w2q[dt][kt] = *(const bf16x4*)((const char*)lds_w2t + byte);
    }
#else
  bf16x8 w2f[2][2];
  #pragma unroll
  for (int dt = 0; dt < 2; ++dt)
    #pragma unroll
    for (int c = 0; c < 2; ++c) {
      int d = dt * 16 + lrow;
      int byte = (d << 7) + ((c * 32 + lg * 8) << 1);
      byte ^= (d & 7) << 4;
      w2f[dt][c] = *(const bf16x8*)((const char*)lds_w2t + byte);
    }
#endif

  const int rem = E - wbase;
  const int nt = rem <= 0 ? 0 : (rem >= 128 ? 8 : ((rem + 15) >> 4));
  if (nt == 0) return;

#if !HAVE_MFMA_K16
  char* hbuf = lds_h[wid];
#endif

  for (int t = 0; t < nt; ++t) {
    const int ebase = wbase + t * 16;

    // consume prefetched tile: convert s to bf16 B-fragments
    bf16x8 sf0, sf1;
    #pragma unroll
    for (int i = 0; i < 4; ++i) {
      sf0[i] = (__bf16)sN[0][i]; sf0[i + 4] = (__bf16)sN[1][i];
      sf1[i] = (__bf16)sN[2][i]; sf1[i + 4] = (__bf16)sN[3][i];
    }
    const f32x4 xe = xN;

    // issue next tile's loads NOW (in flight across all compute below)
    {
      int er = ebase + 16 + lrow; er = er < E ? er : E - 1;
      const float* sp = s + (size_t)er * 64 + lg * 8;
      sN[0] = *(const f32x4*)(sp);
      sN[1] = *(const f32x4*)(sp + 4);
      sN[2] = *(const f32x4*)(sp + 32);
      sN[3] = *(const f32x4*)(sp + 36);
      xN = *(const f32x4*)(x + (size_t)er * 8 + (lg & 1) * 4);
    }

#if HAVE_MFMA_K16
    // ---- GEMM1 -> bf16 quads hq[jt] IN REGISTERS (no LDS, no fences) ----
    // D: col = edge = lrow, row = hid_local = lg*4+r  ->  hq[jt][r] = h[jt*16+lg*4+r]
    bf16x4 hq[4];
    #pragma unroll
    for (int jt = 0; jt < 4; ++jt) {
      const int j = jt * 16 + lrow;
      int wb0 = (j << 7) + ((lg * 8) << 1);      wb0 ^= (j & 7) << 4;
      int wb1 = (j << 7) + ((32 + lg * 8) << 1); wb1 ^= (j & 7) << 4;
      bf16x8 wf0 = *(const bf16x8*)((const char*)lds_w1t + wb0);
      bf16x8 wf1 = *(const bf16x8*)((const char*)lds_w1t + wb1);
      f32x4 acc = bias1[jt];
      acc = MFMA32(wf0, sf0, acc);
      acc = MFMA32(wf1, sf1, acc);
      #pragma unroll
      for (int r = 0; r < 4; ++r) hq[jt][r] = (__bf16)fmaxf(acc[r], 0.f);
    }

    // ---- GEMM2: wT = W2^T @ hT + b2, h as B-frag of 16x16x16 (k=lg*4+i) ----
    float qr[2], qi[2];
    #pragma unroll
    for (int dt = 0; dt < 2; ++dt) {
      f32x4 a = bias2[dt];
      #pragma unroll
      for (int kt = 0; kt < 4; ++kt) a = MFMA16(w2q[dt][kt], hq[kt], a);
      // lane holds w[e=lrow][d = dt*16+lg*4+r]; o=2dt+(lg>>1), p=2(lg&1)+(r>>1)
      float pr = xe[0] * a[0] - xe[1] * a[1] + xe[2] * a[2] - xe[3] * a[3];
      float pi = xe[0] * a[1] + xe[1] * a[0] + xe[2] * a[3] + xe[3] * a[2];
      qr[dt] = pr + __shfl_xor(pr, 16, 64);
      qi[dt] = pi + __shfl_xor(pi, 16, 64);
    }
#else
    // ---- fallback: validated R9 LDS round-trip ----
    #pragma unroll
    for (int jt = 0; jt < 4; ++jt) {
      const int j = jt * 16 + lrow;
      int wb0 = (j << 7) + ((lg * 8) << 1);      wb0 ^= (j & 7) << 4;
      int wb1 = (j << 7) + ((32 + lg * 8) << 1); wb1 ^= (j & 7) << 4;
      bf16x8 wf0 = *(const bf16x8*)((const char*)lds_w1t + wb0);
      bf16x8 wf1 = *(const bf16x8*)((const char*)lds_w1t + wb1);
      f32x4 acc = bias1[jt];
      acc = MFMA32(wf0, sf0, acc);
      acc = MFMA32(wf1, sf1, acc);
      bf16x4 hv;
      #pragma unroll
      for (int r = 0; r < 4; ++r) hv[r] = (__bf16)fmaxf(acc[r], 0.f);
      int byte = (lrow << 7) + ((jt * 16 + lg * 4) << 1);
      byte ^= (lrow & 7) << 4;
      *(bf16x4*)(hbuf + byte) = hv;
    }
    FENCE_WAIT();
    bf16x8 hf0, hf1;
    {
      int b0 = (lrow << 7) + ((lg * 8) << 1);      b0 ^= (lrow & 7) << 4;
      int b1 = (lrow << 7) + ((32 + lg * 8) << 1); b1 ^= (lrow & 7) << 4;
      hf0 = *(const bf16x8*)(hbuf + b0);
      hf1 = *(const bf16x8*)(hbuf + b1);
    }
    FENCE_COMPILER();
    float qr[2], qi[2];
    #pragma unroll
    for (int dt = 0; dt < 2; ++dt) {
      f32x4 a = bias2[dt];
      a = MFMA32(w2f[dt][0], hf0, a);
      a = MFMA32(w2f[dt][1], hf1, a);
      float pr = xe[0] * a[0] - xe[1] * a[1] + xe[2] * a[2] - xe[3] * a[3];
      float pi = xe[0] * a[1] + xe[1] * a[0] + xe[2] * a[3] + xe[3] * a[2];
      qr[dt] = pr + __shfl_xor(pr, 16, 64);
      qi[dt] = pi + __shfl_xor(pi, 16, 64);
    }
#endif

    const int sel = lg & 1;
    const int o = (lg >> 1) + 2 * sel;
    const float vr = sel ? qr[1] : qr[0];
    const float vi = sel ? qi[1] : qi[0];
    const int e = ebase + lrow;
    if (e < E) {
      f32x2 v2 = {vr, vi};
      *(f32x2*)(out + (size_t)e * 8 + o * 2) = v2;
    }
  }
}

extern "C" void kernel_launch(void* const* d_in, const int* in_sizes, int n_in,
                              void* d_out, int out_size, void* d_ws, size_t ws_size,
                              hipStream_t stream) {
  const float* x  = (const float*)d_in[0];
  const float* s  = (const float*)d_in[1];
  const float* W1 = (const float*)d_in[2];
  const float* b1 = (const float*)d_in[3];
  const float* W2 = (const float*)d_in[4];
  const float* b2 = (const float*)d_in[5];
  float* out = (float*)d_out;
  const int E = in_sizes[0] / 8;                 // x is (E, 4, 2)
  const int blocks = (E + 511) / 512;            // 128 edges/wave; ~7.6 blocks/CU
  so2_fused_kernel<<<blocks, 256, 0, stream>>>(x, s, W1, b1, W2, b2, out, E);
}